// Round 1
// baseline (11149.380 us; speedup 1.0000x reference)
//
#include <hip/hip_runtime.h>
#include <math.h>

#define V_  10000
#define E_  256
#define H_  512
#define B_  8
#define S_  512
#define G4H 2048  // 4*H

__device__ __forceinline__ float sigmoidf_(float x) { return 1.f / (1.f + expf(-x)); }

// ---------------------------------------------------------------------------
// K1: pre[m][j] = embed[tok(m)][:] @ w_ih[:, j] + bias[j],  m = s*8+b
// M=4096, K=256, N=2048. Tile 64x64, Ktile 32. grid (64,32), block 256.
// ---------------------------------------------------------------------------
__global__ __launch_bounds__(256, 4) void k_pre(
    const int* __restrict__ tokens, const float* __restrict__ embed,
    const float* __restrict__ w_ih, const float* __restrict__ bias,
    float* __restrict__ pre)
{
  __shared__ float A_lds[64 * 36];  // pad 36 to spread banks
  __shared__ float B_lds[32 * 64];
  __shared__ int   tok_lds[64];
  const int t  = threadIdx.x;
  const int m0 = blockIdx.x * 64;
  const int j0 = blockIdx.y * 64;
  if (t < 64) {
    int m = m0 + t;
    int s = m >> 3, b = m & 7;
    tok_lds[t] = tokens[b * S_ + s];
  }
  __syncthreads();
  const int tx = t & 15, ty = t >> 4;
  const int r_st = t >> 2, q_st = t & 3;   // A staging
  const int kk_st = t >> 3, q2_st = t & 7; // B staging
  float acc[4][4] = {};
  for (int kt = 0; kt < E_; kt += 32) {
    {
      int tok = tok_lds[r_st];
      const float4* src = (const float4*)(embed + (size_t)tok * E_ + kt);
      float4 v0 = src[q_st];
      float4 v1 = src[q_st + 4];
      *(float4*)&A_lds[r_st * 36 + q_st * 4]       = v0;
      *(float4*)&A_lds[r_st * 36 + (q_st + 4) * 4] = v1;
    }
    {
      const float4* src = (const float4*)(w_ih + (size_t)(kt + kk_st) * G4H + j0);
      float4 v0 = src[q2_st];
      float4 v1 = src[q2_st + 8];
      *(float4*)&B_lds[kk_st * 64 + q2_st * 4]       = v0;
      *(float4*)&B_lds[kk_st * 64 + (q2_st + 8) * 4] = v1;
    }
    __syncthreads();
#pragma unroll
    for (int kkg = 0; kkg < 8; ++kkg) {
      float a_[4][4], b_[4][4];
#pragma unroll
      for (int i = 0; i < 4; ++i) {
        float4 av = *(const float4*)&A_lds[(ty * 4 + i) * 36 + kkg * 4];
        a_[i][0] = av.x; a_[i][1] = av.y; a_[i][2] = av.z; a_[i][3] = av.w;
      }
#pragma unroll
      for (int dk = 0; dk < 4; ++dk) {
        float4 bv = *(const float4*)&B_lds[(kkg * 4 + dk) * 64 + tx * 4];
        b_[dk][0] = bv.x; b_[dk][1] = bv.y; b_[dk][2] = bv.z; b_[dk][3] = bv.w;
      }
#pragma unroll
      for (int i = 0; i < 4; ++i)
#pragma unroll
        for (int dk = 0; dk < 4; ++dk)
#pragma unroll
          for (int j = 0; j < 4; ++j)
            acc[i][j] += a_[i][dk] * b_[dk][j];
    }
    __syncthreads();
  }
  const int j = j0 + tx * 4;
  float4 bi = *(const float4*)(bias + j);
#pragma unroll
  for (int i = 0; i < 4; ++i) {
    int m = m0 + ty * 4 + i;
    float4 o;
    o.x = acc[i][0] + bi.x; o.y = acc[i][1] + bi.y;
    o.z = acc[i][2] + bi.z; o.w = acc[i][3] + bi.w;
    *(float4*)&pre[(size_t)m * G4H + j] = o;
  }
}

// ---------------------------------------------------------------------------
// K2: persistent LSTM recurrence. 64 WGs x 512 threads. w_hh in VGPRs.
// WG owns 8 hidden units (u0..u0+7) for all 8 batches; wave = (b-pair, k-half);
// lane = (u_l, kcc): 32 k's per thread, butterfly-reduced over kcc (lane bits 3..5),
// k-half pairs merged in LDS. Double-buffered h + monotone-counter grid barrier.
// ---------------------------------------------------------------------------
__global__ __launch_bounds__(512, 2) void k_rec(
    const float* __restrict__ pre, const float* __restrict__ w_hh,
    float* __restrict__ hbuf,      // [2][B][H], zeroed
    float* __restrict__ hs,        // [S*B][H]
    float* __restrict__ out_tail,  // h_T [B][H] then c_T [B][H]
    unsigned* __restrict__ bar)    // zeroed
{
  __shared__ float sgl[8 * 8 * 8];  // [wave][u_l][b2*4+g]
  const int t    = threadIdx.x;
  const int wg   = blockIdx.x;  // 0..63
  const int u0   = wg * 8;
  const int wave = t >> 6;
  const int lane = t & 63;
  const int bg   = wave & 3;   // b in {2bg, 2bg+1}
  const int kh   = wave >> 2;  // k-half
  const int u_l  = lane & 7;
  const int kcc  = lane >> 3;  // 0..7
  const int k0   = kh * 256 + kcc * 32;
  const int u    = u0 + u_l;

  // preload this thread's w_hh slice: 32 k x 4 gates = 128 VGPRs
  float wreg[32][4];
#pragma unroll
  for (int i = 0; i < 32; ++i) {
    const float* wr = w_hh + (size_t)(k0 + i) * G4H + u;
#pragma unroll
    for (int g = 0; g < 4; ++g) wreg[i][g] = wr[g * 512];
  }

  const int at_b = t >> 3;           // valid for t<64
  const int at_u = u0 + (t & 7);
  float c_state = 0.f;

  for (int s = 0; s < S_; ++s) {
    const float* hrd = hbuf + (s & 1) * (B_ * H_);
    float*       hwr = hbuf + ((s + 1) & 1) * (B_ * H_);

    float pre4[4];
    if (t < 64) {  // prefetch pre for the activation phase (overlaps FMA)
      const float* pp = pre + ((size_t)s * B_ + at_b) * G4H + (t & 7) + u0;
#pragma unroll
      for (int g = 0; g < 4; ++g) pre4[g] = pp[g * 512];
    }

    float4 hva[8], hvb[8];
    {
      const float4* pa = (const float4*)(hrd + (2 * bg + 0) * H_ + k0);
      const float4* pb = (const float4*)(hrd + (2 * bg + 1) * H_ + k0);
#pragma unroll
      for (int i4 = 0; i4 < 8; ++i4) { hva[i4] = pa[i4]; hvb[i4] = pb[i4]; }
    }
    float acc[8] = {};  // [b2*4+g]
#pragma unroll
    for (int i4 = 0; i4 < 8; ++i4) {
      const float ha[4] = {hva[i4].x, hva[i4].y, hva[i4].z, hva[i4].w};
      const float hb[4] = {hvb[i4].x, hvb[i4].y, hvb[i4].z, hvb[i4].w};
#pragma unroll
      for (int e = 0; e < 4; ++e)
#pragma unroll
        for (int g = 0; g < 4; ++g) {
          acc[g]     += wreg[i4 * 4 + e][g] * ha[e];
          acc[4 + g] += wreg[i4 * 4 + e][g] * hb[e];
        }
    }
    // butterfly reduce over kcc (lane bits 3,4,5)
#pragma unroll
    for (int mask = 8; mask <= 32; mask <<= 1)
#pragma unroll
      for (int x = 0; x < 8; ++x) acc[x] += __shfl_xor(acc[x], mask, 64);
    if (kcc == 0) {
#pragma unroll
      for (int x = 0; x < 8; ++x) sgl[(wave * 8 + u_l) * 8 + x] = acc[x];
    }
    __syncthreads();
    if (t < 64) {
      const int bgA = at_b >> 1, b2 = at_b & 1;
      float gv[4];
#pragma unroll
      for (int g = 0; g < 4; ++g)
        gv[g] = sgl[(bgA * 8 + (t & 7)) * 8 + b2 * 4 + g]
              + sgl[((bgA + 4) * 8 + (t & 7)) * 8 + b2 * 4 + g]
              + pre4[g];
      float ig = sigmoidf_(gv[0]);
      float fg = sigmoidf_(gv[1]);
      float gg = tanhf(gv[2]);
      float og = sigmoidf_(gv[3]);
      c_state = fg * c_state + ig * gg;
      float h = og * tanhf(c_state);
      hwr[at_b * H_ + at_u] = h;
      hs[((size_t)s * B_ + at_b) * H_ + at_u] = h;
      if (s == S_ - 1) {
        out_tail[at_b * H_ + at_u]            = h;
        out_tail[B_ * H_ + at_b * H_ + at_u]  = c_state;
      }
    }
    if (s < S_ - 1) {  // grid barrier (monotone counter, no reset needed)
      __threadfence();
      __syncthreads();
      if (t == 0) {
        __hip_atomic_fetch_add(bar, 1u, __ATOMIC_RELEASE, __HIP_MEMORY_SCOPE_AGENT);
        const unsigned target = (unsigned)(s + 1) * 64u;
        while (__hip_atomic_load(bar, __ATOMIC_ACQUIRE, __HIP_MEMORY_SCOPE_AGENT) < target)
          __builtin_amdgcn_s_sleep(1);
      }
      __syncthreads();
      __threadfence();
    }
  }
}

// ---------------------------------------------------------------------------
// K3: out = relu(hs @ w_out + b_out); log_softmax over batch (axis 0), fused.
// M=4096 (rows m=s*8+b), K=512, N=10000. Tile 64x64 => each tile holds 8
// complete batch-groups -> in-LDS logsumexp over the 8 b's. grid (64,157).
// ---------------------------------------------------------------------------
__global__ __launch_bounds__(256, 4) void k_out(
    const float* __restrict__ hs, const float* __restrict__ w_out,
    const float* __restrict__ b_out, float* __restrict__ out)
{
  extern __shared__ float smem[];
  float* A_lds = smem;            // 64*36 = 2304
  float* B_lds = smem + 64 * 36;  // 32*64 = 2048
  const int t  = threadIdx.x;
  const int m0 = blockIdx.x * 64;
  const int n0 = blockIdx.y * 64;
  const int tx = t & 15, ty = t >> 4;
  const int r_st = t >> 2, q_st = t & 3;
  const int kk_st = t >> 3, q2_st = t & 7;
  float acc[4][4] = {};
  for (int kt = 0; kt < H_; kt += 32) {
    {
      const float4* src = (const float4*)(hs + (size_t)(m0 + r_st) * H_ + kt);
      float4 v0 = src[q_st];
      float4 v1 = src[q_st + 4];
      *(float4*)&A_lds[r_st * 36 + q_st * 4]       = v0;
      *(float4*)&A_lds[r_st * 36 + (q_st + 4) * 4] = v1;
    }
    {
      const float* rowp = w_out + (size_t)(kt + kk_st) * V_;
      int nA = n0 + q2_st * 4, nB = n0 + (q2_st + 8) * 4;
      float4 v0 = (nA + 3 < V_) ? *(const float4*)(rowp + nA) : make_float4(0.f, 0.f, 0.f, 0.f);
      float4 v1 = (nB + 3 < V_) ? *(const float4*)(rowp + nB) : make_float4(0.f, 0.f, 0.f, 0.f);
      *(float4*)&B_lds[kk_st * 64 + q2_st * 4]       = v0;
      *(float4*)&B_lds[kk_st * 64 + (q2_st + 8) * 4] = v1;
    }
    __syncthreads();
#pragma unroll
    for (int kkg = 0; kkg < 8; ++kkg) {
      float a_[4][4], b_[4][4];
#pragma unroll
      for (int i = 0; i < 4; ++i) {
        float4 av = *(const float4*)&A_lds[(ty * 4 + i) * 36 + kkg * 4];
        a_[i][0] = av.x; a_[i][1] = av.y; a_[i][2] = av.z; a_[i][3] = av.w;
      }
#pragma unroll
      for (int dk = 0; dk < 4; ++dk) {
        float4 bv = *(const float4*)&B_lds[(kkg * 4 + dk) * 64 + tx * 4];
        b_[dk][0] = bv.x; b_[dk][1] = bv.y; b_[dk][2] = bv.z; b_[dk][3] = bv.w;
      }
#pragma unroll
      for (int i = 0; i < 4; ++i)
#pragma unroll
        for (int dk = 0; dk < 4; ++dk)
#pragma unroll
          for (int j = 0; j < 4; ++j)
            acc[i][j] += a_[i][dk] * b_[dk][j];
    }
    __syncthreads();
  }
  // ---- epilogue: bias + relu -> LDS tile; logsumexp over b; subtract; store
  float* tile = smem;            // [64][65]
  float* lse  = smem + 64 * 65;  // [8][64]
  const int nb = n0 + tx * 4;
  float4 bo = (nb + 3 < V_) ? *(const float4*)(b_out + nb) : make_float4(0.f, 0.f, 0.f, 0.f);
  const float bo_[4] = {bo.x, bo.y, bo.z, bo.w};
  float vreg[4][4];
#pragma unroll
  for (int i = 0; i < 4; ++i)
#pragma unroll
    for (int j = 0; j < 4; ++j) {
      float v = fmaxf(acc[i][j] + bo_[j], 0.f);
      vreg[i][j] = v;
      tile[(ty * 4 + i) * 65 + tx * 4 + j] = v;
    }
  __syncthreads();
#pragma unroll
  for (int rep = 0; rep < 2; ++rep) {
    int idx = t + rep * 256;
    int sg = idx >> 6, c = idx & 63;
    float mx = tile[(sg * 8 + 0) * 65 + c];
#pragma unroll
    for (int b = 1; b < 8; ++b) mx = fmaxf(mx, tile[(sg * 8 + b) * 65 + c]);
    float ssum = 0.f;
#pragma unroll
    for (int b = 0; b < 8; ++b) ssum += expf(tile[(sg * 8 + b) * 65 + c] - mx);
    lse[sg * 64 + c] = mx + logf(ssum);
  }
  __syncthreads();
  if (nb + 3 < V_) {
#pragma unroll
    for (int i = 0; i < 4; ++i) {
      int r = ty * 4 + i;
      int mrow = m0 + r;
      int s = mrow >> 3, b = mrow & 7;
      const float* lp = lse + (r >> 3) * 64 + tx * 4;
      float4 o;
      o.x = vreg[i][0] - lp[0];
      o.y = vreg[i][1] - lp[1];
      o.z = vreg[i][2] - lp[2];
      o.w = vreg[i][3] - lp[3];
      *(float4*)&out[(size_t)b * ((size_t)S_ * V_) + (size_t)s * V_ + nb] = o;
    }
  }
}

// ---------------------------------------------------------------------------
extern "C" void kernel_launch(void* const* d_in, const int* in_sizes, int n_in,
                              void* d_out, int out_size, void* d_ws, size_t ws_size,
                              hipStream_t stream) {
  const int*   tokens = (const int*)d_in[0];
  const float* embed  = (const float*)d_in[1];
  const float* w_ih   = (const float*)d_in[2];
  const float* w_hh   = (const float*)d_in[3];
  const float* bias   = (const float*)d_in[4];
  const float* w_out  = (const float*)d_in[5];
  const float* b_out  = (const float*)d_in[6];
  float* out = (float*)d_out;

  char* ws = (char*)d_ws;
  float*    pre  = (float*)(ws);                              // 33,554,432 B
  float*    hs   = (float*)(ws + 33554432);                   //  8,388,608 B
  float*    hbuf = (float*)(ws + 33554432 + 8388608);         //     32,768 B
  unsigned* bar  = (unsigned*)(ws + 33554432 + 8388608 + 32768);

  // zero h double-buffer + barrier counter (contiguous)
  hipMemsetAsync(hbuf, 0, 2 * B_ * H_ * sizeof(float) + 64, stream);

  k_pre<<<dim3(64, 32), 256, 0, stream>>>(tokens, embed, w_ih, bias, pre);
  k_rec<<<dim3(64), 512, 0, stream>>>(pre, w_hh, hbuf, hs, out + (size_t)B_ * S_ * V_, bar);
  k_out<<<dim3(64, 157), 256, 18688, stream>>>(hs, w_out, b_out, out);
}

// Round 2
// 1585.623 us; speedup vs baseline: 7.0315x; 7.0315x over previous
//
#include <hip/hip_runtime.h>
#include <math.h>

#define V_  10000
#define E_  256
#define H_  512
#define B_  8
#define S_  512
#define G4H 2048  // 4*H

__device__ __forceinline__ float sigmoidf_(float x) { return 1.f / (1.f + expf(-x)); }

// ---------------------------------------------------------------------------
// K1: pre[m][j] = embed[tok(m)][:] @ w_ih[:, j] + bias[j],  m = s*8+b
// M=4096, K=256, N=2048. Tile 64x64, Ktile 32. grid (64,32), block 256.
// ---------------------------------------------------------------------------
__global__ __launch_bounds__(256, 4) void k_pre(
    const int* __restrict__ tokens, const float* __restrict__ embed,
    const float* __restrict__ w_ih, const float* __restrict__ bias,
    float* __restrict__ pre)
{
  __shared__ float A_lds[64 * 36];  // pad 36 to spread banks
  __shared__ float B_lds[32 * 64];
  __shared__ int   tok_lds[64];
  const int t  = threadIdx.x;
  const int m0 = blockIdx.x * 64;
  const int j0 = blockIdx.y * 64;
  if (t < 64) {
    int m = m0 + t;
    int s = m >> 3, b = m & 7;
    tok_lds[t] = tokens[b * S_ + s];
  }
  __syncthreads();
  const int tx = t & 15, ty = t >> 4;
  const int r_st = t >> 2, q_st = t & 3;   // A staging
  const int kk_st = t >> 3, q2_st = t & 7; // B staging
  float acc[4][4] = {};
  for (int kt = 0; kt < E_; kt += 32) {
    {
      int tok = tok_lds[r_st];
      const float4* src = (const float4*)(embed + (size_t)tok * E_ + kt);
      float4 v0 = src[q_st];
      float4 v1 = src[q_st + 4];
      *(float4*)&A_lds[r_st * 36 + q_st * 4]       = v0;
      *(float4*)&A_lds[r_st * 36 + (q_st + 4) * 4] = v1;
    }
    {
      const float4* src = (const float4*)(w_ih + (size_t)(kt + kk_st) * G4H + j0);
      float4 v0 = src[q2_st];
      float4 v1 = src[q2_st + 8];
      *(float4*)&B_lds[kk_st * 64 + q2_st * 4]       = v0;
      *(float4*)&B_lds[kk_st * 64 + (q2_st + 8) * 4] = v1;
    }
    __syncthreads();
#pragma unroll
    for (int kkg = 0; kkg < 8; ++kkg) {
      float a_[4][4], b_[4][4];
#pragma unroll
      for (int i = 0; i < 4; ++i) {
        float4 av = *(const float4*)&A_lds[(ty * 4 + i) * 36 + kkg * 4];
        a_[i][0] = av.x; a_[i][1] = av.y; a_[i][2] = av.z; a_[i][3] = av.w;
      }
#pragma unroll
      for (int dk = 0; dk < 4; ++dk) {
        float4 bv = *(const float4*)&B_lds[(kkg * 4 + dk) * 64 + tx * 4];
        b_[dk][0] = bv.x; b_[dk][1] = bv.y; b_[dk][2] = bv.z; b_[dk][3] = bv.w;
      }
#pragma unroll
      for (int i = 0; i < 4; ++i)
#pragma unroll
        for (int dk = 0; dk < 4; ++dk)
#pragma unroll
          for (int j = 0; j < 4; ++j)
            acc[i][j] += a_[i][dk] * b_[dk][j];
    }
    __syncthreads();
  }
  const int j = j0 + tx * 4;
  float4 bi = *(const float4*)(bias + j);
#pragma unroll
  for (int i = 0; i < 4; ++i) {
    int m = m0 + ty * 4 + i;
    float4 o;
    o.x = acc[i][0] + bi.x; o.y = acc[i][1] + bi.y;
    o.z = acc[i][2] + bi.z; o.w = acc[i][3] + bi.w;
    *(float4*)&pre[(size_t)m * G4H + j] = o;
  }
}

// ---------------------------------------------------------------------------
// K2 (REWRITE): 8 independent batch clusters x 16 WGs x 512 threads. No grid
// barrier, no fences. h exchanged as packed {seq(hi32) | f32 bits(lo32)} u64
// via relaxed agent-scope atomics (per-line coherent at Infinity Cache; no L2
// flush). Parity double-buffer: state s lives in hbuf[s&1]; safe because a
// producer of state s+1 has fully consumed state s => all readers of s-1 done.
// Thread t: unit u_l = t&31 (WG owns units u0=r*32 .. +32), k-chunk kq = t>>5.
// wreg float4[32] = w_hh[k0+i][u + g*512] -> 128 VGPRs, register-resident.
// ---------------------------------------------------------------------------
__global__ __launch_bounds__(512, 2) void k_rec(
    const float* __restrict__ pre, const float* __restrict__ w_hh,
    unsigned long long* __restrict__ hbuf,  // [2][B][H] u64, zeroed (h0=0,seq=0)
    float* __restrict__ hs,                 // [S*B][H]
    float* __restrict__ out_tail)           // h_T [B][H] then c_T [B][H]
{
  __shared__ float h_lds[H_];              // this batch's h (full 512)
  __shared__ float partials[16 * 32 * 4];  // [kq][u_l][g]
  __shared__ float gates_lds[32 * 4];      // [u_l][g]

  const int t   = threadIdx.x;
  const int bid = blockIdx.x;
  const int c   = bid >> 4;   // batch (cluster)
  const int r   = bid & 15;   // rank within cluster
  const int u0  = r * 32;
  const int u_l = t & 31;
  const int kq  = t >> 5;     // 0..15
  const int k0  = kq * 32;
  const int ug  = u0 + u_l;

  // one full w_hh copy per cluster, register-resident: 128 VGPRs/thread
  float4 wreg[32];
#pragma unroll
  for (int i = 0; i < 32; ++i) {
    const float* wr = w_hh + (size_t)(k0 + i) * G4H + ug;
    wreg[i] = make_float4(wr[0], wr[512], wr[1024], wr[1536]);
  }

  const bool is_act = (t < 32);
  float c_state = 0.f;

  for (int s = 0; s < S_; ++s) {
    // prefetch pre for act lanes (normal cached loads; overlaps the poll)
    float p0 = 0.f, p1 = 0.f, p2 = 0.f, p3 = 0.f;
    if (is_act) {
      const float* pp = pre + ((size_t)(s * B_ + c)) * G4H + u0 + t;
      p0 = pp[0]; p1 = pp[512]; p2 = pp[1024]; p3 = pp[1536];
    }
    // poll own h element (payload-fused flag: seq==s means value is state s)
    {
      const unsigned long long* src = hbuf + (((s & 1) * B_ + c) * H_) + t;
      unsigned long long v;
      do {
        v = __hip_atomic_load(src, __ATOMIC_RELAXED, __HIP_MEMORY_SCOPE_AGENT);
      } while ((unsigned)(v >> 32) != (unsigned)s);
      h_lds[t] = __uint_as_float((unsigned)v);
    }
    // FMA over own k-chunk. Wave w reads h_lds[64w..64w+64) = exactly its own
    // lanes' writes -> in-wave lgkmcnt ordering suffices, no __syncthreads.
    float a0 = 0.f, a1 = 0.f, a2 = 0.f, a3 = 0.f;
#pragma unroll
    for (int i = 0; i < 32; ++i) {
      float hv = h_lds[k0 + i];  // half-wave broadcast, conflict-free
      a0 += wreg[i].x * hv; a1 += wreg[i].y * hv;
      a2 += wreg[i].z * hv; a3 += wreg[i].w * hv;
    }
    *(float4*)&partials[t * 4] = make_float4(a0, a1, a2, a3);
    __syncthreads();  // A: partials ready
    if (t < 128) {
      const int uu = t >> 2, g = t & 3;
      float ssum = 0.f;
#pragma unroll
      for (int q = 0; q < 16; ++q) ssum += partials[(q * 32 + uu) * 4 + g];
      gates_lds[t] = ssum;
    }
    __syncthreads();  // B: gates ready (also orders partials WAR for next step)
    if (is_act) {
      float gi = gates_lds[t * 4 + 0] + p0;
      float gf = gates_lds[t * 4 + 1] + p1;
      float gg = gates_lds[t * 4 + 2] + p2;
      float go = gates_lds[t * 4 + 3] + p3;
      float ig = sigmoidf_(gi), fg = sigmoidf_(gf);
      float gt = tanhf(gg),     og = sigmoidf_(go);
      c_state = fg * c_state + ig * gt;
      float h = og * tanhf(c_state);
      hs[((size_t)(s * B_ + c)) * H_ + u0 + t] = h;
      unsigned long long pk =
          ((unsigned long long)(unsigned)(s + 1) << 32) | (unsigned long long)__float_as_uint(h);
      __hip_atomic_store(hbuf + ((((s + 1) & 1) * B_ + c) * H_) + u0 + t, pk,
                         __ATOMIC_RELAXED, __HIP_MEMORY_SCOPE_AGENT);
      if (s == S_ - 1) {
        out_tail[c * H_ + u0 + t]            = h;
        out_tail[B_ * H_ + c * H_ + u0 + t]  = c_state;
      }
    }
  }
}

// ---------------------------------------------------------------------------
// K3: out = relu(hs @ w_out + b_out); log_softmax over batch (axis 0), fused.
// M=4096 (rows m=s*8+b), K=512, N=10000. Tile 64x64 => each tile holds 8
// complete batch-groups -> in-LDS logsumexp over the 8 b's. grid (64,157).
// ---------------------------------------------------------------------------
__global__ __launch_bounds__(256, 4) void k_out(
    const float* __restrict__ hs, const float* __restrict__ w_out,
    const float* __restrict__ b_out, float* __restrict__ out)
{
  extern __shared__ float smem[];
  float* A_lds = smem;            // 64*36 = 2304
  float* B_lds = smem + 64 * 36;  // 32*64 = 2048
  const int t  = threadIdx.x;
  const int m0 = blockIdx.x * 64;
  const int n0 = blockIdx.y * 64;
  const int tx = t & 15, ty = t >> 4;
  const int r_st = t >> 2, q_st = t & 3;
  const int kk_st = t >> 3, q2_st = t & 7;
  float acc[4][4] = {};
  for (int kt = 0; kt < H_; kt += 32) {
    {
      const float4* src = (const float4*)(hs + (size_t)(m0 + r_st) * H_ + kt);
      float4 v0 = src[q_st];
      float4 v1 = src[q_st + 4];
      *(float4*)&A_lds[r_st * 36 + q_st * 4]       = v0;
      *(float4*)&A_lds[r_st * 36 + (q_st + 4) * 4] = v1;
    }
    {
      const float* rowp = w_out + (size_t)(kt + kk_st) * V_;
      int nA = n0 + q2_st * 4, nB = n0 + (q2_st + 8) * 4;
      float4 v0 = (nA + 3 < V_) ? *(const float4*)(rowp + nA) : make_float4(0.f, 0.f, 0.f, 0.f);
      float4 v1 = (nB + 3 < V_) ? *(const float4*)(rowp + nB) : make_float4(0.f, 0.f, 0.f, 0.f);
      *(float4*)&B_lds[kk_st * 64 + q2_st * 4]       = v0;
      *(float4*)&B_lds[kk_st * 64 + (q2_st + 8) * 4] = v1;
    }
    __syncthreads();
#pragma unroll
    for (int kkg = 0; kkg < 8; ++kkg) {
      float a_[4][4], b_[4][4];
#pragma unroll
      for (int i = 0; i < 4; ++i) {
        float4 av = *(const float4*)&A_lds[(ty * 4 + i) * 36 + kkg * 4];
        a_[i][0] = av.x; a_[i][1] = av.y; a_[i][2] = av.z; a_[i][3] = av.w;
      }
#pragma unroll
      for (int dk = 0; dk < 4; ++dk) {
        float4 bv = *(const float4*)&B_lds[(kkg * 4 + dk) * 64 + tx * 4];
        b_[dk][0] = bv.x; b_[dk][1] = bv.y; b_[dk][2] = bv.z; b_[dk][3] = bv.w;
      }
#pragma unroll
      for (int i = 0; i < 4; ++i)
#pragma unroll
        for (int dk = 0; dk < 4; ++dk)
#pragma unroll
          for (int j = 0; j < 4; ++j)
            acc[i][j] += a_[i][dk] * b_[dk][j];
    }
    __syncthreads();
  }
  // ---- epilogue: bias + relu -> LDS tile; logsumexp over b; subtract; store
  float* tile = smem;            // [64][65]
  float* lse  = smem + 64 * 65;  // [8][64]
  const int nb = n0 + tx * 4;
  float4 bo = (nb + 3 < V_) ? *(const float4*)(b_out + nb) : make_float4(0.f, 0.f, 0.f, 0.f);
  const float bo_[4] = {bo.x, bo.y, bo.z, bo.w};
  float vreg[4][4];
#pragma unroll
  for (int i = 0; i < 4; ++i)
#pragma unroll
    for (int j = 0; j < 4; ++j) {
      float v = fmaxf(acc[i][j] + bo_[j], 0.f);
      vreg[i][j] = v;
      tile[(ty * 4 + i) * 65 + tx * 4 + j] = v;
    }
  __syncthreads();
#pragma unroll
  for (int rep = 0; rep < 2; ++rep) {
    int idx = t + rep * 256;
    int sg = idx >> 6, cq = idx & 63;
    float mx = tile[(sg * 8 + 0) * 65 + cq];
#pragma unroll
    for (int b = 1; b < 8; ++b) mx = fmaxf(mx, tile[(sg * 8 + b) * 65 + cq]);
    float ssum = 0.f;
#pragma unroll
    for (int b = 0; b < 8; ++b) ssum += expf(tile[(sg * 8 + b) * 65 + cq] - mx);
    lse[sg * 64 + cq] = mx + logf(ssum);
  }
  __syncthreads();
  if (nb + 3 < V_) {
#pragma unroll
    for (int i = 0; i < 4; ++i) {
      int rr = ty * 4 + i;
      int mrow = m0 + rr;
      int s = mrow >> 3, b = mrow & 7;
      const float* lp = lse + (rr >> 3) * 64 + tx * 4;
      float4 o;
      o.x = vreg[i][0] - lp[0];
      o.y = vreg[i][1] - lp[1];
      o.z = vreg[i][2] - lp[2];
      o.w = vreg[i][3] - lp[3];
      *(float4*)&out[(size_t)b * ((size_t)S_ * V_) + (size_t)s * V_ + nb] = o;
    }
  }
}

// ---------------------------------------------------------------------------
extern "C" void kernel_launch(void* const* d_in, const int* in_sizes, int n_in,
                              void* d_out, int out_size, void* d_ws, size_t ws_size,
                              hipStream_t stream) {
  const int*   tokens = (const int*)d_in[0];
  const float* embed  = (const float*)d_in[1];
  const float* w_ih   = (const float*)d_in[2];
  const float* w_hh   = (const float*)d_in[3];
  const float* bias   = (const float*)d_in[4];
  const float* w_out  = (const float*)d_in[5];
  const float* b_out  = (const float*)d_in[6];
  float* out = (float*)d_out;

  char* ws = (char*)d_ws;
  float*              pre  = (float*)(ws);                      // 33,554,432 B
  float*              hs   = (float*)(ws + 33554432);           //  8,388,608 B
  unsigned long long* hbuf = (unsigned long long*)(ws + 33554432 + 8388608);  // 65,536 B

  // zero the packed h/seq double-buffer (h0 = 0.0f, seq = 0)
  hipMemsetAsync(hbuf, 0, 2 * B_ * H_ * sizeof(unsigned long long), stream);

  k_pre<<<dim3(64, 32), 256, 0, stream>>>(tokens, embed, w_ih, bias, pre);
  k_rec<<<dim3(128), 512, 0, stream>>>(pre, w_hh, hbuf, hs,
                                       out + (size_t)B_ * S_ * V_);
  k_out<<<dim3(64, 157), 256, 18688, stream>>>(hs, w_out, b_out, out);
}

// Round 3
// 1205.706 us; speedup vs baseline: 9.2472x; 1.3151x over previous
//
#include <hip/hip_runtime.h>
#include <math.h>

#define V_  10000
#define E_  256
#define H_  512
#define B_  8
#define S_  512
#define G4H 2048   // 4*H
#define NPAD 10112 // 79*128, padded N for k_out

typedef __attribute__((ext_vector_type(8))) short bf16x8;
typedef __attribute__((ext_vector_type(4))) float f32x4;

__device__ __forceinline__ float sigmoidf_(float x) { return 1.f / (1.f + expf(-x)); }
__device__ __forceinline__ unsigned short f2bf(float x) {
  unsigned u = __float_as_uint(x);
  return (unsigned short)((u + 0x7fffu + ((u >> 16) & 1u)) >> 16);
}
__device__ __forceinline__ float bf2f(unsigned short h) {
  return __uint_as_float(((unsigned)h) << 16);
}

#define GLOAD_LDS16(gsrc, ldst)                                                       \
  __builtin_amdgcn_global_load_lds((const __attribute__((address_space(1))) unsigned*)(gsrc), \
                                   (__attribute__((address_space(3))) unsigned*)(ldst), 16, 0, 0)

// ---------------------------------------------------------------------------
// K1: pre[m][j] = embed[tok(m)][:] @ w_ih[:, j] + bias[j],  m = s*8+b  (fp32)
// ---------------------------------------------------------------------------
__global__ __launch_bounds__(256, 4) void k_pre(
    const int* __restrict__ tokens, const float* __restrict__ embed,
    const float* __restrict__ w_ih, const float* __restrict__ bias,
    float* __restrict__ pre)
{
  __shared__ float A_lds[64 * 36];
  __shared__ float B_lds[32 * 64];
  __shared__ int   tok_lds[64];
  const int t  = threadIdx.x;
  const int m0 = blockIdx.x * 64;
  const int j0 = blockIdx.y * 64;
  if (t < 64) {
    int m = m0 + t;
    int s = m >> 3, b = m & 7;
    tok_lds[t] = tokens[b * S_ + s];
  }
  __syncthreads();
  const int tx = t & 15, ty = t >> 4;
  const int r_st = t >> 2, q_st = t & 3;
  const int kk_st = t >> 3, q2_st = t & 7;
  float acc[4][4] = {};
  for (int kt = 0; kt < E_; kt += 32) {
    {
      int tok = tok_lds[r_st];
      const float4* src = (const float4*)(embed + (size_t)tok * E_ + kt);
      float4 v0 = src[q_st];
      float4 v1 = src[q_st + 4];
      *(float4*)&A_lds[r_st * 36 + q_st * 4]       = v0;
      *(float4*)&A_lds[r_st * 36 + (q_st + 4) * 4] = v1;
    }
    {
      const float4* src = (const float4*)(w_ih + (size_t)(kt + kk_st) * G4H + j0);
      float4 v0 = src[q2_st];
      float4 v1 = src[q2_st + 8];
      *(float4*)&B_lds[kk_st * 64 + q2_st * 4]       = v0;
      *(float4*)&B_lds[kk_st * 64 + (q2_st + 8) * 4] = v1;
    }
    __syncthreads();
#pragma unroll
    for (int kkg = 0; kkg < 8; ++kkg) {
      float a_[4][4], b_[4][4];
#pragma unroll
      for (int i = 0; i < 4; ++i) {
        float4 av = *(const float4*)&A_lds[(ty * 4 + i) * 36 + kkg * 4];
        a_[i][0] = av.x; a_[i][1] = av.y; a_[i][2] = av.z; a_[i][3] = av.w;
      }
#pragma unroll
      for (int dk = 0; dk < 4; ++dk) {
        float4 bv = *(const float4*)&B_lds[(kkg * 4 + dk) * 64 + tx * 4];
        b_[dk][0] = bv.x; b_[dk][1] = bv.y; b_[dk][2] = bv.z; b_[dk][3] = bv.w;
      }
#pragma unroll
      for (int i = 0; i < 4; ++i)
#pragma unroll
        for (int dk = 0; dk < 4; ++dk)
#pragma unroll
          for (int j = 0; j < 4; ++j)
            acc[i][j] += a_[i][dk] * b_[dk][j];
    }
    __syncthreads();
  }
  const int j = j0 + tx * 4;
  float4 bi = *(const float4*)(bias + j);
#pragma unroll
  for (int i = 0; i < 4; ++i) {
    int m = m0 + ty * 4 + i;
    float4 o;
    o.x = acc[i][0] + bi.x; o.y = acc[i][1] + bi.y;
    o.z = acc[i][2] + bi.z; o.w = acc[i][3] + bi.w;
    *(float4*)&pre[(size_t)m * G4H + j] = o;
  }
}

// ---------------------------------------------------------------------------
// K-conv: w_out [512][10000] fp32 -> transposed bf16 hi/lo [NPAD][512], padded
// rows (n >= 10000) are zero. grid (158, 8), block 256.
// ---------------------------------------------------------------------------
__global__ __launch_bounds__(256, 4) void k_wconv(
    const float* __restrict__ w_out,
    unsigned short* __restrict__ wT_hi, unsigned short* __restrict__ wT_lo)
{
  __shared__ float tile[64][65];
  const int t  = threadIdx.x;
  const int n0 = blockIdx.x * 64;
  const int k0 = blockIdx.y * 64;
  const int cn = (t & 15) * 4, rk = t >> 4;
#pragma unroll
  for (int p = 0; p < 4; ++p) {
    int k = k0 + rk + p * 16;
    int n = n0 + cn;
    float v[4];
    if (n + 3 < V_) {
      float4 x = *(const float4*)(w_out + (size_t)k * V_ + n);
      v[0] = x.x; v[1] = x.y; v[2] = x.z; v[3] = x.w;
    } else {
#pragma unroll
      for (int j = 0; j < 4; ++j) v[j] = (n + j < V_) ? w_out[(size_t)k * V_ + n + j] : 0.f;
    }
#pragma unroll
    for (int j = 0; j < 4; ++j) tile[rk + p * 16][cn + j] = v[j];
  }
  __syncthreads();
  const int n_l = t >> 2, kq = t & 3;
  unsigned short hib[16], lob[16];
#pragma unroll
  for (int j = 0; j < 16; ++j) {
    float x = tile[kq * 16 + j][n_l];
    unsigned short h = f2bf(x);
    hib[j] = h;
    lob[j] = f2bf(x - bf2f(h));
  }
  size_t base = (size_t)(n0 + n_l) * 512 + k0 + kq * 16;
#pragma unroll
  for (int q = 0; q < 4; ++q) {
    *(ushort4*)&wT_hi[base + q * 4] = *(ushort4*)&hib[q * 4];
    *(ushort4*)&wT_lo[base + q * 4] = *(ushort4*)&lob[q * 4];
  }
}

// ---------------------------------------------------------------------------
// K2: recurrence (unchanged structure) — now emits hs as bf16 hi/lo.
// ---------------------------------------------------------------------------
__global__ __launch_bounds__(512, 2) void k_rec(
    const float* __restrict__ pre, const float* __restrict__ w_hh,
    unsigned long long* __restrict__ hbuf,  // [2][B][H] u64, zeroed
    unsigned short* __restrict__ hs_hi,     // [S*B][H] bf16
    unsigned short* __restrict__ hs_lo,     // [S*B][H] bf16
    float* __restrict__ out_tail)           // h_T [B][H] then c_T [B][H]
{
  __shared__ float h_lds[H_];
  __shared__ float partials[16 * 32 * 4];
  __shared__ float gates_lds[32 * 4];

  const int t   = threadIdx.x;
  const int bid = blockIdx.x;
  const int c   = bid >> 4;
  const int r   = bid & 15;
  const int u0  = r * 32;
  const int u_l = t & 31;
  const int kq  = t >> 5;
  const int k0  = kq * 32;
  const int ug  = u0 + u_l;

  float4 wreg[32];
#pragma unroll
  for (int i = 0; i < 32; ++i) {
    const float* wr = w_hh + (size_t)(k0 + i) * G4H + ug;
    wreg[i] = make_float4(wr[0], wr[512], wr[1024], wr[1536]);
  }

  const bool is_act = (t < 32);
  float c_state = 0.f;

  for (int s = 0; s < S_; ++s) {
    float p0 = 0.f, p1 = 0.f, p2 = 0.f, p3 = 0.f;
    if (is_act) {
      const float* pp = pre + ((size_t)(s * B_ + c)) * G4H + u0 + t;
      p0 = pp[0]; p1 = pp[512]; p2 = pp[1024]; p3 = pp[1536];
    }
    {
      const unsigned long long* src = hbuf + (((s & 1) * B_ + c) * H_) + t;
      unsigned long long v;
      do {
        v = __hip_atomic_load(src, __ATOMIC_RELAXED, __HIP_MEMORY_SCOPE_AGENT);
      } while ((unsigned)(v >> 32) != (unsigned)s);
      h_lds[t] = __uint_as_float((unsigned)v);
    }
    float a0 = 0.f, a1 = 0.f, a2 = 0.f, a3 = 0.f;
#pragma unroll
    for (int i = 0; i < 32; ++i) {
      float hv = h_lds[k0 + i];
      a0 += wreg[i].x * hv; a1 += wreg[i].y * hv;
      a2 += wreg[i].z * hv; a3 += wreg[i].w * hv;
    }
    *(float4*)&partials[t * 4] = make_float4(a0, a1, a2, a3);
    __syncthreads();
    if (t < 128) {
      const int uu = t >> 2, g = t & 3;
      float ssum = 0.f;
#pragma unroll
      for (int q = 0; q < 16; ++q) ssum += partials[(q * 32 + uu) * 4 + g];
      gates_lds[t] = ssum;
    }
    __syncthreads();
    if (is_act) {
      float gi = gates_lds[t * 4 + 0] + p0;
      float gf = gates_lds[t * 4 + 1] + p1;
      float gg = gates_lds[t * 4 + 2] + p2;
      float go = gates_lds[t * 4 + 3] + p3;
      float ig = sigmoidf_(gi), fg = sigmoidf_(gf);
      float gt = tanhf(gg),     og = sigmoidf_(go);
      c_state = fg * c_state + ig * gt;
      float h = og * tanhf(c_state);
      size_t hidx = ((size_t)(s * B_ + c)) * H_ + u0 + t;
      unsigned short hh = f2bf(h);
      hs_hi[hidx] = hh;
      hs_lo[hidx] = f2bf(h - bf2f(hh));
      unsigned long long pk =
          ((unsigned long long)(unsigned)(s + 1) << 32) | (unsigned long long)__float_as_uint(h);
      __hip_atomic_store(hbuf + ((((s + 1) & 1) * B_ + c) * H_) + u0 + t, pk,
                         __ATOMIC_RELAXED, __HIP_MEMORY_SCOPE_AGENT);
      if (s == S_ - 1) {
        out_tail[c * H_ + u0 + t]            = h;
        out_tail[B_ * H_ + c * H_ + u0 + t]  = c_state;
      }
    }
  }
}

// ---------------------------------------------------------------------------
// K3 (MFMA): out = log_softmax_b(relu(hs @ w_out + b_out)).
// 3-term bf16 split GEMM: AhBh + AhBl + AlBh. Tile 128x128, BK=64, 4 waves
// (each 64x64 = 4x4 frags of 16x16x32). LDS tiles [128][64] bf16, linear for
// global_load_lds; reads XOR-swizzled (c16 ^= r&7) with pre-swizzled global
// source (rule #21). Epilogue: in-register log-softmax over the 8 batch rows
// (partner lanes l and l^16 hold the 8 rows of a group for the same col).
// ---------------------------------------------------------------------------
__global__ __launch_bounds__(256, 2) void k_out(
    const unsigned short* __restrict__ hs_hi, const unsigned short* __restrict__ hs_lo,
    const unsigned short* __restrict__ wT_hi, const unsigned short* __restrict__ wT_lo,
    const float* __restrict__ b_out, float* __restrict__ out)
{
  __shared__ unsigned short lds[4 * 128 * 64];  // A_hi | A_lo | B_hi | B_lo, 64 KB
  char* ldsc = (char*)lds;
  const int t  = threadIdx.x;
  const int w  = t >> 6, l = t & 63;
  const int m0 = blockIdx.x * 128;
  const int n0 = blockIdx.y * 128;
  const int wm = w >> 1, wn = w & 1;
  const int lm = l & 15, lq = l >> 4;

  f32x4 acc[4][4];
#pragma unroll
  for (int fm = 0; fm < 4; ++fm)
#pragma unroll
    for (int fn = 0; fn < 4; ++fn) acc[fm][fn] = (f32x4){0.f, 0.f, 0.f, 0.f};

  for (int kt = 0; kt < H_; kt += 64) {
#pragma unroll
    for (int i = 0; i < 4; ++i) {
      int o   = i * 4096 + w * 1024 + l * 16;  // linear byte offset in a tile
      int r   = o >> 7;                        // row 0..127
      int c16 = (o >> 4) & 7;                  // 16B slot in row
      int cs  = c16 ^ (r & 7);                 // inverse-swizzled source slot
      const unsigned short* sAh = hs_hi + (size_t)(m0 + r) * 512 + kt + cs * 8;
      const unsigned short* sAl = hs_lo + (size_t)(m0 + r) * 512 + kt + cs * 8;
      const unsigned short* sBh = wT_hi + (size_t)(n0 + r) * 512 + kt + cs * 8;
      const unsigned short* sBl = wT_lo + (size_t)(n0 + r) * 512 + kt + cs * 8;
      GLOAD_LDS16(sAh, ldsc + 0     + i * 4096 + w * 1024);
      GLOAD_LDS16(sAl, ldsc + 16384 + i * 4096 + w * 1024);
      GLOAD_LDS16(sBh, ldsc + 32768 + i * 4096 + w * 1024);
      GLOAD_LDS16(sBl, ldsc + 49152 + i * 4096 + w * 1024);
    }
    __syncthreads();  // drains vmcnt before barrier
#pragma unroll
    for (int ks = 0; ks < 2; ++ks) {
      bf16x8 ah[4], al[4], bh[4], bl[4];
#pragma unroll
      for (int f = 0; f < 4; ++f) {
        int ra = wm * 64 + f * 16 + lm;
        int ca = (ks * 4 + lq) ^ (ra & 7);
        ah[f] = *(const bf16x8*)(ldsc + 0     + ra * 128 + ca * 16);
        al[f] = *(const bf16x8*)(ldsc + 16384 + ra * 128 + ca * 16);
        int rb = wn * 64 + f * 16 + lm;
        int cb = (ks * 4 + lq) ^ (rb & 7);
        bh[f] = *(const bf16x8*)(ldsc + 32768 + rb * 128 + cb * 16);
        bl[f] = *(const bf16x8*)(ldsc + 49152 + rb * 128 + cb * 16);
      }
#pragma unroll
      for (int fm = 0; fm < 4; ++fm)
#pragma unroll
        for (int fn = 0; fn < 4; ++fn) {
          acc[fm][fn] = __builtin_amdgcn_mfma_f32_16x16x32_bf16(ah[fm], bh[fn], acc[fm][fn], 0, 0, 0);
          acc[fm][fn] = __builtin_amdgcn_mfma_f32_16x16x32_bf16(ah[fm], bl[fn], acc[fm][fn], 0, 0, 0);
          acc[fm][fn] = __builtin_amdgcn_mfma_f32_16x16x32_bf16(al[fm], bh[fn], acc[fm][fn], 0, 0, 0);
        }
    }
    __syncthreads();
  }

  // ---- epilogue: bias + relu; log-softmax over the 8 batch rows; store
#pragma unroll
  for (int fn = 0; fn < 4; ++fn) {
    const int n = n0 + wn * 64 + fn * 16 + lm;
    const float bo = (n < V_) ? b_out[n] : 0.f;
#pragma unroll
    for (int fm = 0; fm < 4; ++fm) {
      float v[4];
#pragma unroll
      for (int rg = 0; rg < 4; ++rg) v[rg] = fmaxf(acc[fm][fn][rg] + bo, 0.f);
      float mx = fmaxf(fmaxf(v[0], v[1]), fmaxf(v[2], v[3]));
      float gm = fmaxf(mx, __shfl_xor(mx, 16, 64));
      float ss = expf(v[0] - gm) + expf(v[1] - gm) + expf(v[2] - gm) + expf(v[3] - gm);
      float lse = gm + logf(ss + __shfl_xor(ss, 16, 64));
      if (n < V_) {
#pragma unroll
        for (int rg = 0; rg < 4; ++rg) {
          int m = m0 + wm * 64 + fm * 16 + lq * 4 + rg;
          int s = m >> 3, b = m & 7;
          out[(size_t)b * ((size_t)S_ * V_) + (size_t)s * V_ + n] = v[rg] - lse;
        }
      }
    }
  }
}

// ---------------------------------------------------------------------------
extern "C" void kernel_launch(void* const* d_in, const int* in_sizes, int n_in,
                              void* d_out, int out_size, void* d_ws, size_t ws_size,
                              hipStream_t stream) {
  const int*   tokens = (const int*)d_in[0];
  const float* embed  = (const float*)d_in[1];
  const float* w_ih   = (const float*)d_in[2];
  const float* w_hh   = (const float*)d_in[3];
  const float* bias   = (const float*)d_in[4];
  const float* w_out  = (const float*)d_in[5];
  const float* b_out  = (const float*)d_in[6];
  float* out = (float*)d_out;

  char* ws = (char*)d_ws;
  float*              pre   = (float*)(ws);                         // 33,554,432 B
  unsigned short*     hs_hi = (unsigned short*)(ws + 33554432);     //  4,194,304 B
  unsigned short*     hs_lo = (unsigned short*)(ws + 37748736);     //  4,194,304 B
  unsigned short*     wT_hi = (unsigned short*)(ws + 41943040);     // 10,354,688 B
  unsigned short*     wT_lo = (unsigned short*)(ws + 52297728);     // 10,354,688 B
  unsigned long long* hbuf  = (unsigned long long*)(ws + 62652416); //     65,536 B

  hipMemsetAsync(hbuf, 0, 2 * B_ * H_ * sizeof(unsigned long long), stream);

  k_wconv<<<dim3(158, 8), 256, 0, stream>>>(w_out, wT_hi, wT_lo);
  k_pre<<<dim3(64, 32), 256, 0, stream>>>(tokens, embed, w_ih, bias, pre);
  k_rec<<<dim3(128), 512, 0, stream>>>(pre, w_hh, hbuf, hs_hi, hs_lo,
                                       out + (size_t)B_ * S_ * V_);
  k_out<<<dim3(32, 79), 256, 0, stream>>>(hs_hi, hs_lo, wT_hi, wT_lo, b_out, out);
}